// Round 8
// baseline (444.363 us; speedup 1.0000x reference)
//
#include <hip/hip_runtime.h>
#include <math.h>

// Problem constants (match reference)
constexpr int CH         = 64;
constexpr int N_USERS    = 50000;
constexpr int N_ENTITIES = 100000;
constexpr int N_FACTORS  = 4;
constexpr int N_RELM1    = 8;     // N_REL - 1
constexpr int N_EDGES    = 1500000;
constexpr int NNZ        = 800000;

constexpr int NBE        = (N_ENTITIES + 255) / 256;  // 391 coarse buckets (E)
constexpr int NBU        = (N_USERS + 255) / 256;     // 196 coarse buckets (U)
constexpr int NBKT       = NBE + NBU;                 // 587
constexpr int TOTAL      = N_EDGES + NNZ;             // 2.3M items
constexpr int IPB        = 8192;                      // items per count/stage block
constexpr int NBLK       = (TOTAL + IPB - 1) / IPB;   // 281
constexpr int ENT_BLOCKS = N_ENTITIES / 4;            // 25000 (exact)
constexpr int USR_BLOCKS = N_USERS / 4;               // 12500 (exact)

typedef unsigned int u32;

// ---------------------------------------------------------------------------
__device__ __forceinline__ u32 pack_bf16x2(float a, float b) {
    u32 ua = __float_as_uint(a), ub = __float_as_uint(b);
    u32 ra = (ua + 0x7FFFu + ((ua >> 16) & 1u)) >> 16;
    u32 rb = (ub + 0x7FFFu + ((ub >> 16) & 1u)) >> 16;
    return ra | (rb << 16);
}
__device__ __forceinline__ float bf_lo(u32 v) { return __uint_as_float(v << 16); }
__device__ __forceinline__ float bf_hi(u32 v) { return __uint_as_float(v & 0xFFFF0000u); }

__device__ __forceinline__ int coarse_bucket(int i, const int* __restrict__ head,
                                             const int* __restrict__ irows) {
    return (i < N_EDGES) ? (head[i] >> 8) : (NBE + (irows[i - N_EDGES] >> 8));
}

// ---------------------------------------------------------------------------
// A: per-block coarse-bucket histogram -> H[bucket * NBLK + block].
__global__ __launch_bounds__(256)
void count_coarse(const int* __restrict__ head, const int* __restrict__ irows,
                  int* __restrict__ H) {
    __shared__ int hist[NBKT];
    for (int j = threadIdx.x; j < NBKT; j += 256) hist[j] = 0;
    __syncthreads();
    int start = blockIdx.x * IPB;
    int end   = min(start + IPB, TOTAL);
    for (int i = start + threadIdx.x; i < end; i += 256)
        atomicAdd(&hist[coarse_bucket(i, head, irows)], 1);
    __syncthreads();
    for (int j = threadIdx.x; j < NBKT; j += 256)
        H[j * NBLK + blockIdx.x] = hist[j];
}

// B1: one wave per bucket — exclusive scan of H[bucket][0..NBLK), total -> T.
__global__ __launch_bounds__(64)
void scan_hcols(int* __restrict__ H, int* __restrict__ T) {
    int b = blockIdx.x, lane = threadIdx.x;
    int carry = 0;
    #pragma unroll
    for (int c = 0; c < (NBLK + 63) / 64; ++c) {
        int idx = c * 64 + lane;
        int v = (idx < NBLK) ? H[b * NBLK + idx] : 0;
        int incl = v;
        #pragma unroll
        for (int d = 1; d < 64; d <<= 1) {
            int u = __shfl_up(incl, d, 64);
            if (lane >= d) incl += u;
        }
        if (idx < NBLK) H[b * NBLK + idx] = carry + incl - v;
        carry += __shfl(incl, 63, 64);
    }
    if (lane == 0) T[b] = carry;
}

// B2: single block — exclusive scan of T -> Bb, sentinel Bb[NBKT].
__global__ __launch_bounds__(1024)
void scan_buckets(const int* __restrict__ T, int* __restrict__ Bb) {
    __shared__ int lds[1024];
    int t = threadIdx.x;
    int v = (t < NBKT) ? T[t] : 0;
    lds[t] = v;
    __syncthreads();
    for (int d = 1; d < 1024; d <<= 1) {
        int u = (t >= d) ? lds[t - d] : 0;
        __syncthreads();
        lds[t] += u;
        __syncthreads();
    }
    if (t < NBKT) Bb[t] = lds[t] - v;
    if (t == NBKT - 1) Bb[NBKT] = lds[t];
}

// ---------------------------------------------------------------------------
// C: partition into coarse buckets; per-block ranges pre-reserved, LDS atomics.
// Staged entries packed to 4 B: key_lo8 [31:24] | etype [22:20] | tail [19:0].
// User: col [16:0] | key_lo8 [24:17], value in a parallel float array.
__global__ __launch_bounds__(256)
void scatter_stage(const int* __restrict__ head, const int* __restrict__ tail,
                   const int* __restrict__ etype,
                   const int* __restrict__ irows, const int* __restrict__ icols,
                   const float* __restrict__ ivals,
                   const int* __restrict__ H, const int* __restrict__ Bb,
                   u32* __restrict__ stageE, u32* __restrict__ stageUc,
                   float* __restrict__ stageUv) {
    __shared__ int cur[NBKT];
    for (int j = threadIdx.x; j < NBKT; j += 256)
        cur[j] = Bb[j] + H[j * NBLK + blockIdx.x];
    __syncthreads();
    int start = blockIdx.x * IPB;
    int end   = min(start + IPB, TOTAL);
    for (int i = start + threadIdx.x; i < end; i += 256) {
        if (i < N_EDGES) {
            int k = head[i];
            u32 pay = (u32)tail[i] | ((u32)(etype[i] - 1) << 20) | ((u32)(k & 255) << 24);
            int pos = atomicAdd(&cur[k >> 8], 1);
            stageE[pos] = pay;
        } else {
            int ii = i - N_EDGES;
            int k  = irows[ii];
            int pos = atomicAdd(&cur[NBE + (k >> 8)], 1) - N_EDGES;
            stageUc[pos] = (u32)icols[ii] | ((u32)(k & 255) << 17);
            stageUv[pos] = ivals[ii];
        }
    }
}

// ---------------------------------------------------------------------------
// D: one block per bucket; LDS key-hist + scan -> CSR offsets, scatter to CSR.
__global__ __launch_bounds__(256)
void bin_fill(const int* __restrict__ Bb,
              const u32* __restrict__ stageE, const u32* __restrict__ stageUc,
              const float* __restrict__ stageUv,
              int* __restrict__ offE, int* __restrict__ offU,
              int* __restrict__ elst, int* __restrict__ ucol,
              float* __restrict__ uval) {
    __shared__ int khist[256];
    __shared__ int cur[256];
    int b = blockIdx.x, t = threadIdx.x;
    khist[t] = 0;
    __syncthreads();
    if (b < NBE) {
        int lo = Bb[b], hi = Bb[b + 1];
        for (int i = lo + t; i < hi; i += 256)
            atomicAdd(&khist[(stageE[i] >> 24) & 255], 1);
        __syncthreads();
        int v = khist[t];
        for (int d = 1; d < 256; d <<= 1) {
            int u = (t >= d) ? khist[t - d] : 0;
            __syncthreads();
            khist[t] += u;
            __syncthreads();
        }
        int excl = lo + khist[t] - v;
        int key  = b * 256 + t;
        if (key < N_ENTITIES) offE[key] = excl;
        cur[t] = excl;
        __syncthreads();
        for (int i = lo + t; i < hi; i += 256) {
            u32 s = stageE[i];
            int p = atomicAdd(&cur[(s >> 24) & 255], 1);
            elst[p] = (int)(s & 0x00FFFFFFu);   // etype<<20 | tail
        }
        if (b == 0 && t == 0) offE[N_ENTITIES] = N_EDGES;
    } else {
        int lo = Bb[b] - N_EDGES, hi = Bb[b + 1] - N_EDGES;
        for (int i = lo + t; i < hi; i += 256)
            atomicAdd(&khist[(stageUc[i] >> 17) & 255], 1);
        __syncthreads();
        int v = khist[t];
        for (int d = 1; d < 256; d <<= 1) {
            int u = (t >= d) ? khist[t - d] : 0;
            __syncthreads();
            khist[t] += u;
            __syncthreads();
        }
        int excl = lo + khist[t] - v;
        int key  = (b - NBE) * 256 + t;
        if (key < N_USERS) offU[key] = excl;
        cur[t] = excl;
        __syncthreads();
        for (int i = lo + t; i < hi; i += 256) {
            u32 s = stageUc[i];
            float vv = stageUv[i];
            int p = atomicAdd(&cur[(s >> 17) & 255], 1);
            ucol[p] = (int)(s & 0x1FFFFu);
            uval[p] = vv;
        }
        if (b == NBE && t == 0) offU[N_USERS] = NNZ;
    }
}

// ---------------------------------------------------------------------------
// Block 0: disen_weight; Block 1: distance-correlation; blocks >=2: fp32->bf16
// conversion of the entity table (float4 -> 2x packed u32 per thread).
__global__ __launch_bounds__(384)
void discor_cvt(const float* __restrict__ att,
                const float* __restrict__ weight,
                const float* __restrict__ ent_src,
                float* __restrict__ dw,
                float* __restrict__ cor_out,
                u32* __restrict__ entB, int n4) {
    if (blockIdx.x >= 2) {
        int i = (blockIdx.x - 2) * 384 + threadIdx.x;
        if (i < n4) {
            float4 f = ((const float4*)ent_src)[i];
            ((uint2*)entB)[i] = make_uint2(pack_bf16x2(f.x, f.y), pack_bf16x2(f.z, f.w));
        }
        return;
    }
    __shared__ float part[6];
    if (blockIdx.x == 0) {
        if (threadIdx.x < 256) {
            int f = threadIdx.x >> 6;
            int c = threadIdx.x & 63;
            float m = -1e30f;
            #pragma unroll
            for (int j = 0; j < N_RELM1; ++j) m = fmaxf(m, att[f * N_RELM1 + j]);
            float s = 0.0f, w[N_RELM1];
            #pragma unroll
            for (int j = 0; j < N_RELM1; ++j) { w[j] = expf(att[f * N_RELM1 + j] - m); s += w[j]; }
            float acc = 0.0f;
            #pragma unroll
            for (int j = 0; j < N_RELM1; ++j) acc += w[j] * weight[j * CH + c];
            dw[f * CH + c] = acc / s;
        }
    } else {
        int w    = threadIdx.x >> 6;   // 0..5 = pair index
        int lane = threadIdx.x & 63;
        const int pi[6] = {0, 0, 0, 1, 1, 2};
        const int pj[6] = {1, 2, 3, 2, 3, 3};
        int r = lane >> 3, c = lane & 7;
        const float* t1 = att + pi[w] * N_RELM1;
        const float* t2 = att + pj[w] * N_RELM1;
        float a  = sqrtf(fmaxf(t1[r] * t1[r] - 2.0f * t1[r] * t1[c] + t1[c] * t1[c], 0.0f) + 1e-8f);
        float bb = sqrtf(fmaxf(t2[r] * t2[r] - 2.0f * t2[r] * t2[c] + t2[c] * t2[c], 0.0f) + 1e-8f);
        float rsA = a, rsB = bb;
        #pragma unroll
        for (int o = 1; o < 8; o <<= 1) { rsA += __shfl_xor(rsA, o, 64); rsB += __shfl_xor(rsB, o, 64); }
        float csA = a, csB = bb;
        #pragma unroll
        for (int o = 8; o < 64; o <<= 1) { csA += __shfl_xor(csA, o, 64); csB += __shfl_xor(csB, o, 64); }
        float totA = rsA, totB = rsB;
        #pragma unroll
        for (int o = 8; o < 64; o <<= 1) { totA += __shfl_xor(totA, o, 64); totB += __shfl_xor(totB, o, 64); }
        float A = a  - csA * 0.125f - rsA * 0.125f + totA * (1.0f / 64.0f);
        float B = bb - csB * 0.125f - rsB * 0.125f + totB * (1.0f / 64.0f);
        float sAB = A * B, sAA = A * A, sBB = B * B;
        #pragma unroll
        for (int o = 1; o < 64; o <<= 1) {
            sAB += __shfl_xor(sAB, o, 64);
            sAA += __shfl_xor(sAA, o, 64);
            sBB += __shfl_xor(sBB, o, 64);
        }
        if (lane == 0) {
            float dAB = sqrtf(fmaxf(sAB * (1.0f / 64.0f), 0.0f) + 1e-8f);
            float dAA = sqrtf(fmaxf(sAA * (1.0f / 64.0f), 0.0f) + 1e-8f);
            float dBB = sqrtf(fmaxf(sBB * (1.0f / 64.0f), 0.0f) + 1e-8f);
            part[w] = dAB / sqrtf(dAA * dBB + 1e-8f);
        }
        __syncthreads();
        if (threadIdx.x == 0) {
            float s = 0.0f;
            for (int q = 0; q < 6; ++q) s += part[q];
            cor_out[0] = s;
        }
    }
}

// ---------------------------------------------------------------------------
// Fused per-hop pass, bf16 gather table, dwordx4 row fetch.
// Wave = 1 row. oct = lane>>3 picks the edge (8 edges/iter); q = lane&7 picks
// the channel quarter (channels 8q..8q+7 = one uint4 = 4 bf16x2 pairs).
template <bool HOP0>
__global__ __launch_bounds__(256)
void hop_pass(const u32* __restrict__ entB,       // bf16x2 entity table (gathered)
              const float* __restrict__ usr_in,   // fp32 user emb (dense)
              const float* __restrict__ weight, const float* __restrict__ latent,
              const float* __restrict__ dw,
              const int* __restrict__ offE, const int* __restrict__ elst,
              const int* __restrict__ offU, const int* __restrict__ ucol,
              const float* __restrict__ uval,
              u32* __restrict__ AeB_out,          // bf16x2 entity out (hop0)
              float* __restrict__ Au_out,         // fp32 user out (hop0)
              float* __restrict__ ent_res, float* __restrict__ usr_res,
              const float* __restrict__ ent_base, const float* __restrict__ usr_base) {
    __shared__ float4 w_lds[N_RELM1 * 16];
    int lane = threadIdx.x & 63;
    int oct  = lane >> 3;
    int q    = lane & 7;
    if (blockIdx.x < ENT_BLOCKS) {
        if (threadIdx.x < N_RELM1 * 16)
            w_lds[threadIdx.x] = ((const float4*)weight)[threadIdx.x];
        __syncthreads();
        int row = blockIdx.x * 4 + (threadIdx.x >> 6);
        int lo = offE[row], hi = offE[row + 1];
        float acc[8] = {0, 0, 0, 0, 0, 0, 0, 0};
        for (int k0 = lo; k0 < hi; k0 += 64) {
            int m = min(64, hi - k0);
            int p = (lane < m) ? elst[k0 + lane] : 0;
            for (int k = 0; k < m; k += 8) {
                int  kk    = min(k + oct, m - 1);
                bool valid = (k + oct) < m;
                int pk = __shfl(p, kk, 64);
                int tl = pk & 0xFFFFF;
                int et = pk >> 20;
                uint4 x = ((const uint4*)entB)[tl * 8 + q];
                if (!valid) x = make_uint4(0u, 0u, 0u, 0u);
                float4 wA = w_lds[et * 16 + q * 2];
                float4 wB = w_lds[et * 16 + q * 2 + 1];
                acc[0] += bf_lo(x.x) * wA.x; acc[1] += bf_hi(x.x) * wA.y;
                acc[2] += bf_lo(x.y) * wA.z; acc[3] += bf_hi(x.y) * wA.w;
                acc[4] += bf_lo(x.z) * wB.x; acc[5] += bf_hi(x.z) * wB.y;
                acc[6] += bf_lo(x.w) * wB.z; acc[7] += bf_hi(x.w) * wB.w;
            }
        }
        #pragma unroll
        for (int i = 0; i < 8; ++i) {
            acc[i] += __shfl_xor(acc[i], 8, 64);
            acc[i] += __shfl_xor(acc[i], 16, 64);
            acc[i] += __shfl_xor(acc[i], 32, 64);
        }
        float s = 0.0f;
        #pragma unroll
        for (int i = 0; i < 8; ++i) s += acc[i] * acc[i];
        s += __shfl_xor(s, 1, 64); s += __shfl_xor(s, 2, 64); s += __shfl_xor(s, 4, 64);
        float inv = 1.0f / fmaxf(sqrtf(s), 1e-12f);
        if (oct == 0) {
            float y[8];
            #pragma unroll
            for (int i = 0; i < 8; ++i) y[i] = acc[i] * inv;
            int fidx = row * 16 + q * 2;
            if (HOP0) {
                ((uint4*)AeB_out)[row * 8 + q] = make_uint4(
                    pack_bf16x2(y[0], y[1]), pack_bf16x2(y[2], y[3]),
                    pack_bf16x2(y[4], y[5]), pack_bf16x2(y[6], y[7]));
                float4 b0 = ((const float4*)ent_base)[fidx];
                float4 b1 = ((const float4*)ent_base)[fidx + 1];
                ((float4*)ent_res)[fidx]     = make_float4(b0.x + y[0], b0.y + y[1], b0.z + y[2], b0.w + y[3]);
                ((float4*)ent_res)[fidx + 1] = make_float4(b1.x + y[4], b1.y + y[5], b1.z + y[6], b1.w + y[7]);
            } else {
                float4 r0 = ((const float4*)ent_res)[fidx];
                float4 r1 = ((const float4*)ent_res)[fidx + 1];
                ((float4*)ent_res)[fidx]     = make_float4(r0.x + y[0], r0.y + y[1], r0.z + y[2], r0.w + y[3]);
                ((float4*)ent_res)[fidx + 1] = make_float4(r1.x + y[4], r1.y + y[5], r1.z + y[6], r1.w + y[7]);
            }
        }
    } else {
        int row = (blockIdx.x - ENT_BLOCKS) * 4 + (threadIdx.x >> 6);
        int fidx = row * 16 + q * 2;
        float4 u0 = ((const float4*)usr_in)[fidx];
        float4 u1 = ((const float4*)usr_in)[fidx + 1];
        float d[4];
        #pragma unroll
        for (int f = 0; f < 4; ++f) {
            float4 l0 = ((const float4*)latent)[f * 16 + q * 2];
            float4 l1 = ((const float4*)latent)[f * 16 + q * 2 + 1];
            d[f] = u0.x * l0.x + u0.y * l0.y + u0.z * l0.z + u0.w * l0.w
                 + u1.x * l1.x + u1.y * l1.y + u1.z * l1.z + u1.w * l1.w;
            d[f] += __shfl_xor(d[f], 1, 64);
            d[f] += __shfl_xor(d[f], 2, 64);
            d[f] += __shfl_xor(d[f], 4, 64);
        }
        float mx = fmaxf(fmaxf(d[0], d[1]), fmaxf(d[2], d[3]));
        float e0 = expf(d[0] - mx), e1 = expf(d[1] - mx);
        float e2 = expf(d[2] - mx), e3 = expf(d[3] - mx);
        float sinv = 1.0f / (e0 + e1 + e2 + e3);
        float mix[8];
        {
            float4 w00 = ((const float4*)dw)[0 * 16 + q * 2], w01 = ((const float4*)dw)[0 * 16 + q * 2 + 1];
            float4 w10 = ((const float4*)dw)[1 * 16 + q * 2], w11 = ((const float4*)dw)[1 * 16 + q * 2 + 1];
            float4 w20 = ((const float4*)dw)[2 * 16 + q * 2], w21 = ((const float4*)dw)[2 * 16 + q * 2 + 1];
            float4 w30 = ((const float4*)dw)[3 * 16 + q * 2], w31 = ((const float4*)dw)[3 * 16 + q * 2 + 1];
            mix[0] = (e0 * w00.x + e1 * w10.x + e2 * w20.x + e3 * w30.x) * sinv;
            mix[1] = (e0 * w00.y + e1 * w10.y + e2 * w20.y + e3 * w30.y) * sinv;
            mix[2] = (e0 * w00.z + e1 * w10.z + e2 * w20.z + e3 * w30.z) * sinv;
            mix[3] = (e0 * w00.w + e1 * w10.w + e2 * w20.w + e3 * w30.w) * sinv;
            mix[4] = (e0 * w01.x + e1 * w11.x + e2 * w21.x + e3 * w31.x) * sinv;
            mix[5] = (e0 * w01.y + e1 * w11.y + e2 * w21.y + e3 * w31.y) * sinv;
            mix[6] = (e0 * w01.z + e1 * w11.z + e2 * w21.z + e3 * w31.z) * sinv;
            mix[7] = (e0 * w01.w + e1 * w11.w + e2 * w21.w + e3 * w31.w) * sinv;
        }
        float acc[8] = {0, 0, 0, 0, 0, 0, 0, 0};
        int lo = offU[row], hi = offU[row + 1];
        for (int k0 = lo; k0 < hi; k0 += 64) {
            int m = min(64, hi - k0);
            int   cl = (lane < m) ? ucol[k0 + lane] : 0;
            float vv = (lane < m) ? uval[k0 + lane] : 0.0f;
            for (int k = 0; k < m; k += 8) {
                int  kk    = min(k + oct, m - 1);
                bool valid = (k + oct) < m;
                int   ck = __shfl(cl, kk, 64);
                float vk = __shfl(vv, kk, 64);
                if (!valid) vk = 0.0f;
                uint4 x = ((const uint4*)entB)[ck * 8 + q];
                acc[0] += vk * bf_lo(x.x); acc[1] += vk * bf_hi(x.x);
                acc[2] += vk * bf_lo(x.y); acc[3] += vk * bf_hi(x.y);
                acc[4] += vk * bf_lo(x.z); acc[5] += vk * bf_hi(x.z);
                acc[6] += vk * bf_lo(x.w); acc[7] += vk * bf_hi(x.w);
            }
        }
        #pragma unroll
        for (int i = 0; i < 8; ++i) {
            acc[i] += __shfl_xor(acc[i], 8, 64);
            acc[i] += __shfl_xor(acc[i], 16, 64);
            acc[i] += __shfl_xor(acc[i], 32, 64);
        }
        float un[8];
        float s = 0.0f;
        #pragma unroll
        for (int i = 0; i < 8; ++i) { un[i] = acc[i] * (1.0f + mix[i]); s += un[i] * un[i]; }
        s += __shfl_xor(s, 1, 64); s += __shfl_xor(s, 2, 64); s += __shfl_xor(s, 4, 64);
        float inv = 1.0f / fmaxf(sqrtf(s), 1e-12f);
        if (oct == 0) {
            float y[8];
            #pragma unroll
            for (int i = 0; i < 8; ++i) y[i] = un[i] * inv;
            if (HOP0) {
                ((float4*)Au_out)[fidx]     = make_float4(y[0], y[1], y[2], y[3]);
                ((float4*)Au_out)[fidx + 1] = make_float4(y[4], y[5], y[6], y[7]);
                float4 b0 = ((const float4*)usr_base)[fidx];
                float4 b1 = ((const float4*)usr_base)[fidx + 1];
                ((float4*)usr_res)[fidx]     = make_float4(b0.x + y[0], b0.y + y[1], b0.z + y[2], b0.w + y[3]);
                ((float4*)usr_res)[fidx + 1] = make_float4(b1.x + y[4], b1.y + y[5], b1.z + y[6], b1.w + y[7]);
            } else {
                float4 r0 = ((const float4*)usr_res)[fidx];
                float4 r1 = ((const float4*)usr_res)[fidx + 1];
                ((float4*)usr_res)[fidx]     = make_float4(r0.x + y[0], r0.y + y[1], r0.z + y[2], r0.w + y[3]);
                ((float4*)usr_res)[fidx + 1] = make_float4(r1.x + y[4], r1.y + y[5], r1.z + y[6], r1.w + y[7]);
            }
        }
    }
}

// ---------------------------------------------------------------------------
extern "C" void kernel_launch(void* const* d_in, const int* in_sizes, int n_in,
                              void* d_out, int out_size, void* d_ws, size_t ws_size,
                              hipStream_t stream) {
    const float* user_emb   = (const float*)d_in[0];
    const float* entity_emb = (const float*)d_in[1];
    const float* latent     = (const float*)d_in[2];
    const float* weight     = (const float*)d_in[3];
    const float* att        = (const float*)d_in[4];
    const float* ivals      = (const float*)d_in[5];
    const int*   head       = (const int*)d_in[6];
    const int*   tail       = (const int*)d_in[7];
    const int*   etype      = (const int*)d_in[8];
    const int*   irows      = (const int*)d_in[9];
    const int*   icols      = (const int*)d_in[10];

    float* out     = (float*)d_out;
    float* ent_res = out;
    float* usr_res = out + (size_t)N_ENTITIES * CH;
    float* cor_out = out + (size_t)N_ENTITIES * CH + (size_t)N_USERS * CH;

    const size_t ENT_ELEMS = (size_t)N_ENTITIES * CH;   // 6.4M
    const size_t USR_ELEMS = (size_t)N_USERS * CH;      // 3.2M
    const int    ENT_PAIRS = (int)(ENT_ELEMS / 2);      // 3.2M u32
    const int    ENT_QUADS = (int)(ENT_ELEMS / 4);      // 1.6M float4

    // Workspace carve-up (~52 MB).
    // CSR staging (12.4 MB) aliases the AeB region (12.8 MB): staging is dead
    // after bin_fill, before hop0 writes AeB. entB is written by discor_cvt
    // up front and never aliased.
    float* ws   = (float*)d_ws;
    u32*   entB = (u32*)ws;                         // 3.2M u32 (12.8 MB)
    u32*   AeB  = entB + ENT_PAIRS;                 // 3.2M u32 (12.8 MB)
    float* Au   = (float*)(AeB + ENT_PAIRS);        // 3.2M f32 (12.8 MB)
    float* dw   = Au + USR_ELEMS;                   // 4x64
    int*   offE = (int*)(dw + N_FACTORS * CH);      // 100001
    int*   offU = offE + N_ENTITIES + 1;            // 50001
    int*   elst = offU + N_USERS + 1;               // 1.5M packed
    int*   ucol = elst + N_EDGES;                   // 800K
    float* uval = (float*)(ucol + NNZ);             // 800K
    int*   H    = (int*)(uval + NNZ);               // NBKT*NBLK = 164947
    int*   T    = H + NBKT * NBLK;                  // 587
    int*   Bb   = T + NBKT;                         // 588
    // Staging aliased on AeB: 1.5M + 800K + 800K u32/f32 = 12.4 MB < 12.8 MB
    u32*   stageE  = AeB;
    u32*   stageUc = stageE + N_EDGES;
    float* stageUv = (float*)(stageUc + NNZ);

    // ---- dw + cor + bf16 conversion (independent of CSR build) ----
    const int cvtBlocks = (ENT_QUADS + 383) / 384;
    discor_cvt<<<2 + cvtBlocks, 384, 0, stream>>>(att, weight, entity_emb,
                                                  dw, cor_out, entB, ENT_QUADS);

    // ---- Build CSR (no global atomics, no memsets) ----
    count_coarse<<<NBLK, 256, 0, stream>>>(head, irows, H);
    scan_hcols<<<NBKT, 64, 0, stream>>>(H, T);
    scan_buckets<<<1, 1024, 0, stream>>>(T, Bb);
    scatter_stage<<<NBLK, 256, 0, stream>>>(head, tail, etype, irows, icols, ivals,
                                            H, Bb, stageE, stageUc, stageUv);
    bin_fill<<<NBKT, 256, 0, stream>>>(Bb, stageE, stageUc, stageUv,
                                       offE, offU, elst, ucol, uval);

    // ---- Hop 0 (gathers entB; writes AeB bf16 + Au fp32 + residuals) ----
    hop_pass<true><<<ENT_BLOCKS + USR_BLOCKS, 256, 0, stream>>>(
        entB, user_emb, weight, latent, dw,
        offE, elst, offU, ucol, uval,
        AeB, Au, ent_res, usr_res, entity_emb, user_emb);

    // ---- Hop 1 (gathers AeB) ----
    hop_pass<false><<<ENT_BLOCKS + USR_BLOCKS, 256, 0, stream>>>(
        AeB, Au, weight, latent, dw,
        offE, elst, offU, ucol, uval,
        nullptr, nullptr, ent_res, usr_res, nullptr, nullptr);
}